// Round 1
// baseline (759.087 us; speedup 1.0000x reference)
//
#include <hip/hip_runtime.h>
#include <hip/hip_bf16.h>

#define NATOMS 2048
#define K 48
#define P (NATOMS * K)
#define NR 5
#define NM 12
#define ND 17
#define HID 64

#define PI_F 3.14159265358979f
#define CUT 3.0f
#define RMIN_F 3.5f
#define AFC (-6.28318530717959f)   /* pi/(CUT-RMIN) = pi/(-0.5) */
#define POC (PI_F / CUT)           /* pi/3 */
#define SQ 0.816496580927726f      /* sqrt(2/3) */

// Scratch in device globals (fully rewritten every call before any read).
__device__ float g_desc[ND * P];   // transposed: [feature][pair]
__device__ float g_gdesc[ND * P];  // transposed: [feature][pair]
__device__ float g_eij[P];

__device__ __forceinline__ float fast_tanh(float x) {
    float cx = fminf(fmaxf(x, -15.0f), 15.0f);
    float t = __expf(2.0f * cx);
    return (t - 1.0f) / (t + 1.0f);
}

// ---------------- Kernel 1: per-atom forward (rbf + 3-body descriptors) ---
__global__ __launch_bounds__(256) void k_fwd_atom(const float* __restrict__ rij) {
    __shared__ float su[K][3];
    __shared__ float sfcrik[K];
    __shared__ float sc[K][K + 1];
    const int atom = blockIdx.x, t = threadIdx.x, base = atom * K;

    if (t < K) {
        const float x = rij[3 * (base + t) + 0];
        const float y = rij[3 * (base + t) + 1];
        const float z = rij[3 * (base + t) + 2];
        const float d = sqrtf(x * x + y * y + z * z);
        const float inv = 1.0f / fmaxf(d, 1e-12f);
        su[t][0] = x * inv; su[t][1] = y * inv; su[t][2] = z * inv;
        sfcrik[t] = 0.5f + 0.5f * __cosf(POC * d);
        const float fc = (d > RMIN_F) ? (0.5f + 0.5f * __cosf(AFC * (d - RMIN_F))) : 1.0f;
        const float s = SQ * fc / d;
#pragma unroll
        for (int n = 0; n < NR; n++) {
            const float bn = (float)(n + 1) * POC;
            g_desc[n * P + base + t] = s * __sinf(bn * d);
        }
    }
    __syncthreads();

    for (int idx = t; idx < K * K; idx += 256) {
        const int k = idx / K, l = idx - k * K;
        const float c = su[k][0] * su[l][0] + su[k][1] * su[l][1] + su[k][2] * su[l][2];
        sc[k][l] = (k == l) ? 0.0f : c;
    }
    __syncthreads();

    for (int idx = t; idx < K * NM; idx += 256) {
        const int k = idx / NM, m = idx - k * NM;
        const float mu = -1.0f + (2.0f / 11.0f) * (float)m;
        float s = 0.0f;
#pragma unroll 4
        for (int l = 0; l < K; l++) {
            const float df = sc[k][l] - mu;
            s = fmaf(__expf(-4.0f * df * df), sfcrik[l], s);
        }
        g_desc[(NR + m) * P + base + k] = s;
    }
}

// ---------------- Kernel 2: per-pair MLP forward + backward ---------------
__global__ __launch_bounds__(256, 2) void k_mlp(const float* __restrict__ rij,
                                                const float* __restrict__ W1,
                                                const float* __restrict__ b1,
                                                const float* __restrict__ W2,
                                                const float* __restrict__ b2,
                                                const float* __restrict__ W3,
                                                const float* __restrict__ b3) {
    const int p = blockIdx.x * 256 + threadIdx.x;

    float dsc[ND];
#pragma unroll
    for (int j = 0; j < ND; j++) dsc[j] = g_desc[j * P + p];

    const float x = rij[3 * p], y = rij[3 * p + 1], z = rij[3 * p + 2];
    const float d = sqrtf(x * x + y * y + z * z);
    const float fc = (d > RMIN_F) ? (0.5f + 0.5f * __cosf(AFC * (d - RMIN_F))) : 1.0f;

    // layer 1
    float a[HID];
#pragma unroll
    for (int h = 0; h < HID; h++) a[h] = b1[h];
#pragma unroll
    for (int j = 0; j < ND; j++) {
        const float dj = dsc[j];
#pragma unroll
        for (int h = 0; h < HID; h++) a[h] = fmaf(dj, W1[j * HID + h], a[h]);
    }
    float h1v[HID];
#pragma unroll
    for (int h = 0; h < HID; h++) h1v[h] = fast_tanh(a[h]);

    // layer 2
    float a2[HID];
#pragma unroll
    for (int h = 0; h < HID; h++) a2[h] = b2[h];
#pragma unroll
    for (int j = 0; j < HID; j++) {
        const float hj = h1v[j];
#pragma unroll
        for (int h = 0; h < HID; h++) a2[h] = fmaf(hj, W2[j * HID + h], a2[h]);
    }

    // layer 3 + eij
    float e = b3[0];
#pragma unroll
    for (int h = 0; h < HID; h++) {
        a2[h] = fast_tanh(a2[h]);
        e = fmaf(a2[h], W3[h], e);
    }
    g_eij[p] = e;

    // backward: gz2 (in a2)
#pragma unroll
    for (int h = 0; h < HID; h++) a2[h] = fc * W3[h] * (1.0f - a2[h] * a2[h]);

    // gz1 (in h1v)
#pragma unroll
    for (int j = 0; j < HID; j++) {
        float s = 0.0f;
#pragma unroll
        for (int h = 0; h < HID; h++) s = fmaf(a2[h], W2[j * HID + h], s);
        h1v[j] = s * (1.0f - h1v[j] * h1v[j]);
    }

    // gdesc
#pragma unroll
    for (int j = 0; j < ND; j++) {
        float s = 0.0f;
#pragma unroll
        for (int h = 0; h < HID; h++) s = fmaf(h1v[h], W1[j * HID + h], s);
        g_gdesc[j * P + p] = s;
    }
}

// ---------------- Kernel 3: per-atom backward -----------------------------
__global__ __launch_bounds__(256) void k_bwd_atom(const float* __restrict__ rij,
                                                  float* __restrict__ out) {
    __shared__ float su[K][3];
    __shared__ float sd_[K];
    __shared__ float sfcrik[K];
    __shared__ float sS[K][K + 1];
    __shared__ float sT[K][K + 1];
    __shared__ float sgG[K][NM];
    __shared__ float sgu[K][3];
    __shared__ float sgf[K];
    const int atom = blockIdx.x, t = threadIdx.x, base = atom * K;

    if (t < K) {
        const float x = rij[3 * (base + t) + 0];
        const float y = rij[3 * (base + t) + 1];
        const float z = rij[3 * (base + t) + 2];
        const float d = sqrtf(x * x + y * y + z * z);
        const float inv = 1.0f / fmaxf(d, 1e-12f);
        su[t][0] = x * inv; su[t][1] = y * inv; su[t][2] = z * inv;
        sd_[t] = d;
        sfcrik[t] = 0.5f + 0.5f * __cosf(POC * d);
    }
    for (int idx = t; idx < K * NM; idx += 256) {
        const int k = idx / NM, m = idx - k * NM;
        sgG[k][m] = g_gdesc[(NR + m) * P + base + k];
    }
    __syncthreads();

    // cosang into sS
    for (int idx = t; idx < K * K; idx += 256) {
        const int k = idx / K, l = idx - k * K;
        const float c = su[k][0] * su[l][0] + su[k][1] * su[l][1] + su[k][2] * su[l][2];
        sS[k][l] = (k == l) ? 0.0f : c;
    }
    __syncthreads();

    // S and T (each entry owned by exactly one thread -> in-place safe)
    for (int idx = t; idx < K * K; idx += 256) {
        const int k = idx / K, l = idx - k * K;
        const float c = sS[k][l];
        float Ss = 0.0f, Ts = 0.0f;
#pragma unroll
        for (int m = 0; m < NM; m++) {
            const float mu = -1.0f + (2.0f / 11.0f) * (float)m;
            const float df = c - mu;
            const float e2 = __expf(-4.0f * df * df);
            const float g = sgG[k][m];
            Ts = fmaf(g, e2, Ts);
            Ss = fmaf(g * df, e2, Ss);
        }
        sT[k][l] = Ts;
        sS[k][l] = (k == l) ? 0.0f : (-8.0f) * Ss;  // -2*eta = -8
    }
    __syncthreads();

    // reductions: gfcrik (wave 0) and gu (wave 1)
    if (t < K) {
        float s = 0.0f;
#pragma unroll 4
        for (int kk = 0; kk < K; kk++) s += sT[kk][t];
        sgf[t] = s;
    } else if (t >= 64 && t < 64 + K) {
        const int k = t - 64;
        const float fk = sfcrik[k];
        float gx = 0.0f, gy = 0.0f, gz = 0.0f;
#pragma unroll 4
        for (int l = 0; l < K; l++) {
            const float w = fmaf(sS[k][l], sfcrik[l], sS[l][k] * fk);
            gx = fmaf(w, su[l][0], gx);
            gy = fmaf(w, su[l][1], gy);
            gz = fmaf(w, su[l][2], gz);
        }
        sgu[k][0] = gx; sgu[k][1] = gy; sgu[k][2] = gz;
    }
    __syncthreads();

    if (t < K) {
        const float d = sd_[t];
        const float ux = su[t][0], uy = su[t][1], uz = su[t][2];
        const float invd = 1.0f / d;
        float gfc = g_eij[base + t];
        float gdR = 0.0f;
#pragma unroll
        for (int n = 0; n < NR; n++) {
            const float bn = (float)(n + 1) * POC;
            float sn, cn;
            __sincosf(bn * d, &sn, &cn);
            const float g = g_gdesc[n * P + base + t];
            gfc = fmaf(g, SQ * sn * invd, gfc);
            gdR = fmaf(g, SQ * (bn * cn - sn * invd) * invd, gdR);
        }
        float fc, dfc;
        if (d > RMIN_F) {
            float sa, ca;
            __sincosf(AFC * (d - RMIN_F), &sa, &ca);
            fc = 0.5f + 0.5f * ca;
            dfc = -0.5f * AFC * sa;
        } else { fc = 1.0f; dfc = 0.0f; }
        const float dfcrik = -0.5f * POC * __sinf(POC * d);

        const float gd = fc * gdR + gfc * dfc + sgf[t] * dfcrik;
        const float gux = sgu[t][0], guy = sgu[t][1], guz = sgu[t][2];
        const float dot = gux * ux + guy * uy + guz * uz;

        out[3 * (base + t) + 0] = fmaf(gd, ux, (gux - dot * ux) * invd);
        out[3 * (base + t) + 1] = fmaf(gd, uy, (guy - dot * uy) * invd);
        out[3 * (base + t) + 2] = fmaf(gd, uz, (guz - dot * uz) * invd);
    }
}

extern "C" void kernel_launch(void* const* d_in, const int* in_sizes, int n_in,
                              void* d_out, int out_size, void* d_ws, size_t ws_size,
                              hipStream_t stream) {
    (void)in_sizes; (void)n_in; (void)out_size; (void)d_ws; (void)ws_size;
    const float* rij = (const float*)d_in[0];
    // d_in[1] = unique_i (unused: dense K neighbors per atom)
    const float* W1 = (const float*)d_in[2];
    const float* b1 = (const float*)d_in[3];
    const float* W2 = (const float*)d_in[4];
    const float* b2 = (const float*)d_in[5];
    const float* W3 = (const float*)d_in[6];
    const float* b3 = (const float*)d_in[7];
    float* out = (float*)d_out;

    k_fwd_atom<<<NATOMS, 256, 0, stream>>>(rij);
    k_mlp<<<P / 256, 256, 0, stream>>>(rij, W1, b1, W2, b2, W3, b3);
    k_bwd_atom<<<NATOMS, 256, 0, stream>>>(rij, out);
}

// Round 2
// 594.437 us; speedup vs baseline: 1.2770x; 1.2770x over previous
//
#include <hip/hip_runtime.h>
#include <hip/hip_bf16.h>

#define NATOMS 2048
#define K 48
#define P (NATOMS * K)
#define NR 5
#define NM 12
#define ND 17
#define HID 64

#define PI_F 3.14159265358979f
#define CUT 3.0f
#define RMIN_F 3.5f
#define AFC (-6.28318530717959f)   /* pi/(CUT-RMIN) = pi/(-0.5) */
#define POC (PI_F / CUT)           /* pi/3 */
#define SQ 0.816496580927726f      /* sqrt(2/3) */

// Scratch in device globals (fully rewritten every call before any read).
__device__ float g_desc[ND * P];   // transposed: [feature][pair]
__device__ float g_gdesc[ND * P];  // transposed: [feature][pair]
__device__ float g_eij[P];

__device__ __forceinline__ float fast_tanh(float x) {
    float cx = fminf(fmaxf(x, -15.0f), 15.0f);
    float t = __expf(2.0f * cx);
    return (t - 1.0f) / (t + 1.0f);
}

// ---------------- Kernel 1: per-atom forward (rbf + 3-body descriptors) ---
__global__ __launch_bounds__(256) void k_fwd_atom(const float* __restrict__ rij) {
    __shared__ float su[K][3];
    __shared__ float sfcrik[K];
    __shared__ float sc[K][K + 1];
    const int atom = blockIdx.x, t = threadIdx.x, base = atom * K;

    if (t < K) {
        const float x = rij[3 * (base + t) + 0];
        const float y = rij[3 * (base + t) + 1];
        const float z = rij[3 * (base + t) + 2];
        const float d = sqrtf(x * x + y * y + z * z);
        const float inv = 1.0f / fmaxf(d, 1e-12f);
        su[t][0] = x * inv; su[t][1] = y * inv; su[t][2] = z * inv;
        sfcrik[t] = 0.5f + 0.5f * __cosf(POC * d);
        const float fc = (d > RMIN_F) ? (0.5f + 0.5f * __cosf(AFC * (d - RMIN_F))) : 1.0f;
        const float s = SQ * fc / d;
#pragma unroll
        for (int n = 0; n < NR; n++) {
            const float bn = (float)(n + 1) * POC;
            g_desc[n * P + base + t] = s * __sinf(bn * d);
        }
    }
    __syncthreads();

    for (int idx = t; idx < K * K; idx += 256) {
        const int k = idx / K, l = idx - k * K;
        const float c = su[k][0] * su[l][0] + su[k][1] * su[l][1] + su[k][2] * su[l][2];
        sc[k][l] = (k == l) ? 0.0f : c;
    }
    __syncthreads();

    for (int idx = t; idx < K * NM; idx += 256) {
        const int k = idx / NM, m = idx - k * NM;
        const float mu = -1.0f + (2.0f / 11.0f) * (float)m;
        float s = 0.0f;
#pragma unroll 4
        for (int l = 0; l < K; l++) {
            const float df = sc[k][l] - mu;
            s = fmaf(__expf(-4.0f * df * df), sfcrik[l], s);
        }
        g_desc[(NR + m) * P + base + k] = s;
    }
}

// ---------------- Kernel 2: per-pair MLP forward + backward ---------------
// __launch_bounds__(256,1): do NOT cap VGPRs — live set ~135 floats; a 128-VGPR
// cap caused 180 MB of scratch spill traffic (= 640 us) in round 1.
__global__ __launch_bounds__(256, 1) void k_mlp(const float* __restrict__ rij,
                                                const float* __restrict__ W1,
                                                const float* __restrict__ b1,
                                                const float* __restrict__ W2,
                                                const float* __restrict__ b2,
                                                const float* __restrict__ W3,
                                                const float* __restrict__ b3) {
    const int p = blockIdx.x * 256 + threadIdx.x;

    const float x = rij[3 * p], y = rij[3 * p + 1], z = rij[3 * p + 2];
    const float d = sqrtf(x * x + y * y + z * z);
    const float fc = (d > RMIN_F) ? (0.5f + 0.5f * __cosf(AFC * (d - RMIN_F))) : 1.0f;

    // layer 1 (h1 holds pre-act, then tanh in place)
    float h1[HID];
#pragma unroll
    for (int h = 0; h < HID; h++) h1[h] = b1[h];
    {
        float dsc[ND];
#pragma unroll
        for (int j = 0; j < ND; j++) dsc[j] = g_desc[j * P + p];
#pragma unroll
        for (int j = 0; j < ND; j++) {
            const float dj = dsc[j];
#pragma unroll
            for (int h = 0; h < HID; h++) h1[h] = fmaf(dj, W1[j * HID + h], h1[h]);
        }
    }
#pragma unroll
    for (int h = 0; h < HID; h++) h1[h] = fast_tanh(h1[h]);

    // layer 2 (a2 pre-act, then tanh in place)
    float a2[HID];
#pragma unroll
    for (int h = 0; h < HID; h++) a2[h] = b2[h];
#pragma unroll
    for (int j = 0; j < HID; j++) {
        const float hj = h1[j];
#pragma unroll
        for (int h = 0; h < HID; h++) a2[h] = fmaf(hj, W2[j * HID + h], a2[h]);
    }

    // layer 3 + eij
    float e = b3[0];
#pragma unroll
    for (int h = 0; h < HID; h++) {
        a2[h] = fast_tanh(a2[h]);
        e = fmaf(a2[h], W3[h], e);
    }
    g_eij[p] = e;

    // backward: gz2 in place of a2
#pragma unroll
    for (int h = 0; h < HID; h++) a2[h] = fc * W3[h] * (1.0f - a2[h] * a2[h]);

    // gz1 in place of h1
#pragma unroll
    for (int j = 0; j < HID; j++) {
        float s = 0.0f;
#pragma unroll
        for (int h = 0; h < HID; h++) s = fmaf(a2[h], W2[j * HID + h], s);
        h1[j] = s * (1.0f - h1[j] * h1[j]);
    }

    // gdesc
#pragma unroll
    for (int j = 0; j < ND; j++) {
        float s = 0.0f;
#pragma unroll
        for (int h = 0; h < HID; h++) s = fmaf(h1[h], W1[j * HID + h], s);
        g_gdesc[j * P + p] = s;
    }
}

// ---------------- Kernel 3: per-atom backward -----------------------------
__global__ __launch_bounds__(256) void k_bwd_atom(const float* __restrict__ rij,
                                                  float* __restrict__ out) {
    __shared__ float su[K][3];
    __shared__ float sd_[K];
    __shared__ float sfcrik[K];
    __shared__ float sS[K][K + 1];
    __shared__ float sT[K][K + 1];
    __shared__ float sgG[K][NM];
    __shared__ float sgu[K][3];
    __shared__ float sgf[K];
    const int atom = blockIdx.x, t = threadIdx.x, base = atom * K;

    if (t < K) {
        const float x = rij[3 * (base + t) + 0];
        const float y = rij[3 * (base + t) + 1];
        const float z = rij[3 * (base + t) + 2];
        const float d = sqrtf(x * x + y * y + z * z);
        const float inv = 1.0f / fmaxf(d, 1e-12f);
        su[t][0] = x * inv; su[t][1] = y * inv; su[t][2] = z * inv;
        sd_[t] = d;
        sfcrik[t] = 0.5f + 0.5f * __cosf(POC * d);
    }
    for (int idx = t; idx < K * NM; idx += 256) {
        const int k = idx / NM, m = idx - k * NM;
        sgG[k][m] = g_gdesc[(NR + m) * P + base + k];
    }
    __syncthreads();

    // cosang into sS
    for (int idx = t; idx < K * K; idx += 256) {
        const int k = idx / K, l = idx - k * K;
        const float c = su[k][0] * su[l][0] + su[k][1] * su[l][1] + su[k][2] * su[l][2];
        sS[k][l] = (k == l) ? 0.0f : c;
    }
    __syncthreads();

    // S and T (each entry owned by exactly one thread -> in-place safe)
    for (int idx = t; idx < K * K; idx += 256) {
        const int k = idx / K, l = idx - k * K;
        const float c = sS[k][l];
        float Ss = 0.0f, Ts = 0.0f;
#pragma unroll
        for (int m = 0; m < NM; m++) {
            const float mu = -1.0f + (2.0f / 11.0f) * (float)m;
            const float df = c - mu;
            const float e2 = __expf(-4.0f * df * df);
            const float g = sgG[k][m];
            Ts = fmaf(g, e2, Ts);
            Ss = fmaf(g * df, e2, Ss);
        }
        sT[k][l] = Ts;
        sS[k][l] = (k == l) ? 0.0f : (-8.0f) * Ss;  // -2*eta = -8
    }
    __syncthreads();

    // reductions: gfcrik (wave 0) and gu (wave 1)
    if (t < K) {
        float s = 0.0f;
#pragma unroll 4
        for (int kk = 0; kk < K; kk++) s += sT[kk][t];
        sgf[t] = s;
    } else if (t >= 64 && t < 64 + K) {
        const int k = t - 64;
        const float fk = sfcrik[k];
        float gx = 0.0f, gy = 0.0f, gz = 0.0f;
#pragma unroll 4
        for (int l = 0; l < K; l++) {
            const float w = fmaf(sS[k][l], sfcrik[l], sS[l][k] * fk);
            gx = fmaf(w, su[l][0], gx);
            gy = fmaf(w, su[l][1], gy);
            gz = fmaf(w, su[l][2], gz);
        }
        sgu[k][0] = gx; sgu[k][1] = gy; sgu[k][2] = gz;
    }
    __syncthreads();

    if (t < K) {
        const float d = sd_[t];
        const float ux = su[t][0], uy = su[t][1], uz = su[t][2];
        const float invd = 1.0f / d;
        float gfc = g_eij[base + t];
        float gdR = 0.0f;
#pragma unroll
        for (int n = 0; n < NR; n++) {
            const float bn = (float)(n + 1) * POC;
            float sn, cn;
            __sincosf(bn * d, &sn, &cn);
            const float g = g_gdesc[n * P + base + t];
            gfc = fmaf(g, SQ * sn * invd, gfc);
            gdR = fmaf(g, SQ * (bn * cn - sn * invd) * invd, gdR);
        }
        float fc, dfc;
        if (d > RMIN_F) {
            float sa, ca;
            __sincosf(AFC * (d - RMIN_F), &sa, &ca);
            fc = 0.5f + 0.5f * ca;
            dfc = -0.5f * AFC * sa;
        } else { fc = 1.0f; dfc = 0.0f; }
        const float dfcrik = -0.5f * POC * __sinf(POC * d);

        const float gd = fc * gdR + gfc * dfc + sgf[t] * dfcrik;
        const float gux = sgu[t][0], guy = sgu[t][1], guz = sgu[t][2];
        const float dot = gux * ux + guy * uy + guz * uz;

        out[3 * (base + t) + 0] = fmaf(gd, ux, (gux - dot * ux) * invd);
        out[3 * (base + t) + 1] = fmaf(gd, uy, (guy - dot * uy) * invd);
        out[3 * (base + t) + 2] = fmaf(gd, uz, (guz - dot * uz) * invd);
    }
}

extern "C" void kernel_launch(void* const* d_in, const int* in_sizes, int n_in,
                              void* d_out, int out_size, void* d_ws, size_t ws_size,
                              hipStream_t stream) {
    (void)in_sizes; (void)n_in; (void)out_size; (void)d_ws; (void)ws_size;
    const float* rij = (const float*)d_in[0];
    // d_in[1] = unique_i (unused: dense K neighbors per atom)
    const float* W1 = (const float*)d_in[2];
    const float* b1 = (const float*)d_in[3];
    const float* W2 = (const float*)d_in[4];
    const float* b2 = (const float*)d_in[5];
    const float* W3 = (const float*)d_in[6];
    const float* b3 = (const float*)d_in[7];
    float* out = (float*)d_out;

    k_fwd_atom<<<NATOMS, 256, 0, stream>>>(rij);
    k_mlp<<<P / 256, 256, 0, stream>>>(rij, W1, b1, W2, b2, W3, b3);
    k_bwd_atom<<<NATOMS, 256, 0, stream>>>(rij, out);
}